// Round 7
// baseline (62.799 us; speedup 1.0000x reference)
//
#include <hip/hip_runtime.h>
#include <hip/hip_bf16.h>
#include <math.h>

#define BB 8
#define NN 2048
#define HH 768
#define D1 128
#define D2 64
#define BN (BB*NN)            // 16384 rows total
#define NCH 16                // split-n chunks for S1 partial reduction
#define ROWS_PER_CH (NN/NCH)  // 128

// workspace offsets (floats)
#define OFF_XNB   0u          // bf16 [BN][128]
#define OFF_XNBT  1048576u    // bf16 [8][128][2048]
#define OFF_NRM   2097152u    // f32  [BN]
#define OFF_W2    2113536u    // f32  [BN]   (h1 . c2_lw per row)
#define OFF_T2V   2129920u    // f32  [BN]   (h1 . r2 per row)
#define OFF_P1    2146304u    // f32 [8][16][128][128]  (w1b bf16 aliases here pre-s1)
#define OFF_M1T   4243456u    // bf16 [8][64][128]
#define OFF_R1T   4276224u    // bf16 [64][128]
#define OFF_M2F   4280320u    // f32 [8][128]
#define OFF_R2F   4281344u    // f32 [64]
#define OFF_CTR   4281408u    // u32 [16]  (8 for s1m1, 8 for m2out)

typedef __attribute__((ext_vector_type(8))) short short8v;
typedef __attribute__((ext_vector_type(4))) float f32x4;
typedef unsigned short USH;

__device__ __forceinline__ USH f2bf(float f) {
  unsigned int u = __builtin_bit_cast(unsigned int, f);
  u = (u + 0x7fffu + ((u >> 16) & 1u)) >> 16;
  return (USH)u;
}
__device__ __forceinline__ float bf2f(USH u) {
  return __builtin_bit_cast(float, ((unsigned int)u) << 16);
}

#define GLDS16(gp, lp)                                                        \
  __builtin_amdgcn_global_load_lds((const __attribute__((address_space(1))) void*)(gp), \
                                   (__attribute__((address_space(3))) void*)(lp), 16, 0, 0)

// device-scope batch-local barrier: `expected` blocks release into ctr, all wait.
__device__ __forceinline__ void batch_barrier(unsigned* ctr, unsigned expected) {
  __syncthreads();
  if (threadIdx.x == 0) {
    __hip_atomic_fetch_add(ctr, 1u, __ATOMIC_RELEASE, __HIP_MEMORY_SCOPE_AGENT);
    while (__hip_atomic_load(ctr, __ATOMIC_ACQUIRE, __HIP_MEMORY_SCOPE_AGENT) < expected) {}
  }
  __syncthreads();
}

// ---------------- K0: prep — w1->bf16, R1T, r2, zero barrier counters ----------------
__global__ __launch_bounds__(256) void k_prep(const float* __restrict__ w1,
                                              const float* __restrict__ c1_lw,
                                              const float* __restrict__ c1_rw,
                                              const float* __restrict__ c2_lw,
                                              const float* __restrict__ c2_rw,
                                              USH* __restrict__ w1b,
                                              USH* __restrict__ R1T,
                                              float* __restrict__ r2f,
                                              unsigned* __restrict__ ctr) {
  const int bid = blockIdx.x, t = threadIdx.x;
  const float inv = 1.0f / 2047.0f;
  if (bid < 96) {
    int i = (bid * 256 + t) * 4;
    float4 v = *reinterpret_cast<const float4*>(&w1[i]);
    ushort4 o;
    o.x = f2bf(v.x); o.y = f2bf(v.y); o.z = f2bf(v.z); o.w = f2bf(v.w);
    *reinterpret_cast<ushort4*>(&w1b[i]) = o;
  } else if (bid < 98) {
    int base = (bid - 96) * 4096 + t * 16;
#pragma unroll
    for (int k = 0; k < 16; ++k) {
      int i = base + k;
      R1T[i] = f2bf(c1_rw[i] - c1_lw[i] * inv);
    }
  } else {
    if (t < D2) r2f[t] = c2_rw[t] - c2_lw[t] * inv;
    if (t >= 64 && t < 80) ctr[t - 64] = 0u;
  }
}

// ---------------- K1: h = x @ w1^T + b1 (bf16 MFMA, BM=32 BK=64, swizzled LDS) --------
// emits xnb [n][128], xnbT [b][128][2048], nrm [n]   (h == xn * nrm, never stored)
__global__ __launch_bounds__(256) void k_gemm_h(const float* __restrict__ x,
                                                const USH* __restrict__ w1b,
                                                const float* __restrict__ b1,
                                                USH* __restrict__ xnb,
                                                USH* __restrict__ xnbT,
                                                float* __restrict__ nrm) {
  __shared__ __align__(16) USH As[2][32][64];   // 8 KB  (slot-swizzled)
  __shared__ __align__(16) USH Bs[2][128][64];  // 32 KB (slot-swizzled)
  __shared__ float norms[32][2];
  __shared__ __align__(16) USH T[128][40];      // 10 KB transpose buffer

  const int t = threadIdx.x;
  const int w = t >> 6, l = t & 63;
  const int wm = w & 1, wn = w >> 1;
  const int row0 = blockIdx.x * 32;
  const int b_ = row0 >> 11, nloc = row0 & (NN - 1);

  const int arow = t >> 3, aseg = t & 7;
  const int aslot = aseg ^ (arow & 7);
  const size_t xbase = (size_t)(row0 + arow) * HH;
  const int brow_l = w * 32 + (l >> 3);

  f32x4 acc[4] = {};

  {  // prologue: buffer 0
#pragma unroll
    for (int q = 0; q < 4; ++q) {
      int brow = brow_l + q * 8;
      int gslot = (l & 7) ^ (brow & 7);
      GLDS16(w1b + (size_t)brow * HH + gslot * 8, &Bs[0][w * 32 + q * 8][0]);
    }
    float4 xa = *reinterpret_cast<const float4*>(&x[xbase + aseg * 8]);
    float4 xb = *reinterpret_cast<const float4*>(&x[xbase + aseg * 8 + 4]);
    short8v v;
    v[0] = (short)f2bf(xa.x); v[1] = (short)f2bf(xa.y);
    v[2] = (short)f2bf(xa.z); v[3] = (short)f2bf(xa.w);
    v[4] = (short)f2bf(xb.x); v[5] = (short)f2bf(xb.y);
    v[6] = (short)f2bf(xb.z); v[7] = (short)f2bf(xb.w);
    *reinterpret_cast<short8v*>(&As[0][arow][aslot * 8]) = v;
  }

  for (int kt = 0; kt < HH / 64; ++kt) {
    const int cur = kt & 1, nxt = cur ^ 1;
    __syncthreads();

    float4 xa, xb;
    if (kt < HH / 64 - 1) {
      const int k0n = (kt + 1) * 64;
#pragma unroll
      for (int q = 0; q < 4; ++q) {
        int brow = brow_l + q * 8;
        int gslot = (l & 7) ^ (brow & 7);
        GLDS16(w1b + (size_t)brow * HH + k0n + gslot * 8, &Bs[nxt][w * 32 + q * 8][0]);
      }
      xa = *reinterpret_cast<const float4*>(&x[xbase + k0n + aseg * 8]);
      xb = *reinterpret_cast<const float4*>(&x[xbase + k0n + aseg * 8 + 4]);
    }

    const int ar = wm * 16 + (l & 15);
#pragma unroll
    for (int ks = 0; ks < 2; ++ks) {
      short8v a = *reinterpret_cast<const short8v*>(
          &As[cur][ar][((ks * 4 + (l >> 4)) ^ (ar & 7)) * 8]);
#pragma unroll
      for (int ni = 0; ni < 4; ++ni) {
        int br = wn * 64 + ni * 16 + (l & 15);
        short8v b = *reinterpret_cast<const short8v*>(
            &Bs[cur][br][((ks * 4 + (l >> 4)) ^ (br & 7)) * 8]);
        acc[ni] = __builtin_amdgcn_mfma_f32_16x16x32_bf16(a, b, acc[ni], 0, 0, 0);
      }
    }

    if (kt < HH / 64 - 1) {
      short8v v;
      v[0] = (short)f2bf(xa.x); v[1] = (short)f2bf(xa.y);
      v[2] = (short)f2bf(xa.z); v[3] = (short)f2bf(xa.w);
      v[4] = (short)f2bf(xb.x); v[5] = (short)f2bf(xb.y);
      v[6] = (short)f2bf(xb.z); v[7] = (short)f2bf(xb.w);
      *reinterpret_cast<short8v*>(&As[nxt][arow][aslot * 8]) = v;
    }
  }

  // epilogue: bias, row-norm, write xnb + xnbT + nrm
  float bv[4];
#pragma unroll
  for (int ni = 0; ni < 4; ++ni) bv[ni] = b1[wn * 64 + ni * 16 + (l & 15)];
#pragma unroll
  for (int ni = 0; ni < 4; ++ni)
#pragma unroll
    for (int r = 0; r < 4; ++r) acc[ni][r] += bv[ni];

#pragma unroll
  for (int r = 0; r < 4; ++r) {
    float s = 0.f;
#pragma unroll
    for (int ni = 0; ni < 4; ++ni) { float v = acc[ni][r]; s += v * v; }
#pragma unroll
    for (int m = 1; m < 16; m <<= 1) s += __shfl_xor(s, m, 64);
    if ((l & 15) == 0) norms[wm * 16 + (l >> 4) * 4 + r][wn] = s;
  }
  __syncthreads();

#pragma unroll
  for (int r = 0; r < 4; ++r) {
    int row = wm * 16 + (l >> 4) * 4 + r;
    float tot = norms[row][0] + norms[row][1];
    float ncl = fmaxf(sqrtf(tot), 1e-8f);
    float inv = 1.0f / ncl;
    if (wn == 0 && (l & 15) == 0) nrm[row0 + row] = ncl;
    size_t gbase = (size_t)(row0 + row) * D1;
#pragma unroll
    for (int ni = 0; ni < 4; ++ni) {
      int col = wn * 64 + ni * 16 + (l & 15);
      USH xv = f2bf(acc[ni][r] * inv);
      xnb[gbase + col] = xv;
      T[col][row] = xv;
    }
  }
  __syncthreads();
  {
    int d = t >> 1, seg = t & 1;
    size_t g = ((size_t)b_ * D1 + d) * NN + nloc + seg * 16;
    *reinterpret_cast<short8v*>(&xnbT[g]) =
        *reinterpret_cast<const short8v*>(&T[d][seg * 16]);
    *reinterpret_cast<short8v*>(&xnbT[g + 8]) =
        *reinterpret_cast<const short8v*>(&T[d][seg * 16 + 8]);
  }
}

// ---------------- K2: fused S1-partials (MFMA) + barrier + M1T slice --------------------
// grid (16 ch, 8 b), 256 threads. Phase 1 writes P1 chunk; phase 2 (after per-batch
// barrier over the 16 chunk-blocks) reduces rows ch*8..+7 and emits M1T.
__global__ __launch_bounds__(256) void k_s1m1(const USH* __restrict__ xnbT,
                                              const float* __restrict__ nrm,
                                              const float* __restrict__ c1_lw,
                                              float* __restrict__ P1,
                                              USH* __restrict__ M1T,
                                              unsigned* __restrict__ ctr) {
  __shared__ __align__(16) char smem[69632];   // phase1: TA/TB; phase2: lw_s/s_s
  short (*TA)[136] = (short(*)[136])smem;
  short (*TB)[136] = (short(*)[136])(smem + 128 * 136 * 2);
  float (*lw_s)[132] = (float(*)[132])smem;                 // 33.8 KB
  float (*s_s)[128]  = (float(*)[128])(smem + 33792);       // 4 KB

  const int t = threadIdx.x;
  const int ch = blockIdx.x, b = blockIdx.y;
  const int n0 = ch * ROWS_PER_CH;

  // ---- phase 1: S1 partial chunk via MFMA ----
  {
    const int r0 = t >> 4;
    const int c8 = (t & 15) * 8;
    float4 nva = *reinterpret_cast<const float4*>(&nrm[(size_t)b * NN + n0 + c8]);
    float4 nvb = *reinterpret_cast<const float4*>(&nrm[(size_t)b * NN + n0 + c8 + 4]);
    float nv[8] = {nva.x, nva.y, nva.z, nva.w, nvb.x, nvb.y, nvb.z, nvb.w};
#pragma unroll
    for (int p = 0; p < 8; ++p) {
      int row = p * 16 + r0;
      short8v v = *reinterpret_cast<const short8v*>(&xnbT[((size_t)b * D1 + row) * NN + n0 + c8]);
      *reinterpret_cast<short8v*>(&TA[row][c8]) = v;
      short8v hv;
#pragma unroll
      for (int j = 0; j < 8; ++j) hv[j] = (short)f2bf(bf2f((USH)v[j]) * nv[j]);
      *reinterpret_cast<short8v*>(&TB[row][c8]) = hv;
    }
  }
  __syncthreads();
  {
    const int w = t >> 6, l = t & 63;
    const int wm = w & 1, wn = w >> 1;
    f32x4 acc[4][4] = {};
#pragma unroll
    for (int ks = 0; ks < 4; ++ks) {
      short8v a[4], bb[4];
#pragma unroll
      for (int fi = 0; fi < 4; ++fi)
        a[fi] = *reinterpret_cast<const short8v*>(&TA[wm * 64 + fi * 16 + (l & 15)][ks * 32 + (l >> 4) * 8]);
#pragma unroll
      for (int fj = 0; fj < 4; ++fj)
        bb[fj] = *reinterpret_cast<const short8v*>(&TB[wn * 64 + fj * 16 + (l & 15)][ks * 32 + (l >> 4) * 8]);
#pragma unroll
      for (int fi = 0; fi < 4; ++fi)
#pragma unroll
        for (int fj = 0; fj < 4; ++fj)
          acc[fi][fj] = __builtin_amdgcn_mfma_f32_16x16x32_bf16(a[fi], bb[fj], acc[fi][fj], 0, 0, 0);
    }
    float* P = P1 + ((size_t)b * NCH + ch) * (D1 * D1);
#pragma unroll
    for (int fi = 0; fi < 4; ++fi)
#pragma unroll
      for (int fj = 0; fj < 4; ++fj)
#pragma unroll
        for (int r = 0; r < 4; ++r) {
          int row = wm * 64 + fi * 16 + (l >> 4) * 4 + r;
          int col = wn * 64 + fj * 16 + (l & 15);
          P[(size_t)row * D1 + col] = acc[fi][fj][r];
        }
  }

  // ---- stage c1_lw into (reused) LDS before spinning ----
  __syncthreads();   // everyone done reading TA/TB
#pragma unroll
  for (int q = 0; q < 8; ++q) {
    int idx4 = q * 256 + t;
    int o = idx4 >> 5, e4 = idx4 & 31;
    float4 v = *reinterpret_cast<const float4*>(&c1_lw[o * 128 + e4 * 4]);
    *reinterpret_cast<float4*>(&lw_s[o][e4 * 4]) = v;
  }

  // ---- per-batch barrier across the 16 chunk blocks ----
  batch_barrier(&ctr[b], 16u);

  // ---- phase 2: reduce P1 rows ch*8..+7, dot with lw, write M1T ----
  const float inv = 1.0f / 2047.0f;
  const float* Pb = P1 + (size_t)b * NCH * (D1 * D1) + (size_t)(ch * 8) * D1;
  {
    int r = t >> 5, e4 = t & 31;
    float4 s = make_float4(0.f, 0.f, 0.f, 0.f);
#pragma unroll
    for (int c = 0; c < NCH; ++c) {
      float4 v = *reinterpret_cast<const float4*>(&Pb[(size_t)c * (D1 * D1) + r * D1 + e4 * 4]);
      s.x += v.x; s.y += v.y; s.z += v.z; s.w += v.w;
    }
    *reinterpret_cast<float4*>(&s_s[r][e4 * 4]) = s;
  }
  __syncthreads();
  {
    const int row = t >> 5;           // 0..7
    const int ox = t & 31;            // o and o+32
    float a0 = 0.f, a1 = 0.f;
    for (int e4 = 0; e4 < 32; ++e4) {
      float4 lw0 = *reinterpret_cast<const float4*>(&lw_s[ox][e4 * 4]);
      float4 lw1 = *reinterpret_cast<const float4*>(&lw_s[ox + 32][e4 * 4]);
      float4 sv = *reinterpret_cast<const float4*>(&s_s[row][e4 * 4]);
      a0 += sv.x * lw0.x + sv.y * lw0.y + sv.z * lw0.z + sv.w * lw0.w;
      a1 += sv.x * lw1.x + sv.y * lw1.y + sv.z * lw1.z + sv.w * lw1.w;
    }
    int d = ch * 8 + row;
    M1T[((size_t)b * D2 + ox) * D1 + d]      = f2bf(a0 * inv);
    M1T[((size_t)b * D2 + ox + 32) * D1 + d] = f2bf(a1 * inv);
  }
}

// ---------------- K3: h1 = relu([xn | nrm*xn] @ [M1T|R1T]^T + c1_lb) (K=256 MFMA) ------
// epilogue reduces h1 rows against c2_lw and r2 -> w2[n], t2[n] (fp32). No h1 stored.
__global__ __launch_bounds__(256) void k_h1(const USH* __restrict__ xnb,
                                            const float* __restrict__ nrm,
                                            const USH* __restrict__ M1T,
                                            const USH* __restrict__ R1T,
                                            const float* __restrict__ c1_lb,
                                            const float* __restrict__ c2_lw,
                                            const float* __restrict__ r2f,
                                            float* __restrict__ w2,
                                            float* __restrict__ t2v) {
  __shared__ __align__(16) short TA[64][280];
  __shared__ __align__(16) short TB[64][280];
  __shared__ float ws2[64][2], ts2[64][2];
  const int t = threadIdx.x;
  const int row0 = blockIdx.x * 64;
  const int b = row0 >> 11;
  {
    const int row = t >> 2, seg = t & 3;
    const float nr = nrm[row0 + row];
#pragma unroll
    for (int j = 0; j < 4; ++j) {
      int e = seg * 32 + j * 8;
      short8v v = *reinterpret_cast<const short8v*>(&xnb[(size_t)(row0 + row) * D1 + e]);
      *reinterpret_cast<short8v*>(&TA[row][e]) = v;
      short8v sv;
#pragma unroll
      for (int jj = 0; jj < 8; ++jj) sv[jj] = (short)f2bf(bf2f((USH)v[jj]) * nr);
      *reinterpret_cast<short8v*>(&TA[row][128 + e]) = sv;
      *reinterpret_cast<short8v*>(&TB[row][e]) =
          *reinterpret_cast<const short8v*>(&M1T[((size_t)b * D2 + row) * D1 + e]);
      *reinterpret_cast<short8v*>(&TB[row][128 + e]) =
          *reinterpret_cast<const short8v*>(&R1T[(size_t)row * D1 + e]);
    }
  }
  __syncthreads();
  const int w = t >> 6, l = t & 63;
  const int wm = w & 1, wn = w >> 1;
  f32x4 acc[2][2] = {};
#pragma unroll
  for (int ks = 0; ks < 8; ++ks) {
    short8v a[2], bb[2];
#pragma unroll
    for (int i = 0; i < 2; ++i)
      a[i] = *reinterpret_cast<const short8v*>(&TA[wm * 32 + i * 16 + (l & 15)][ks * 32 + (l >> 4) * 8]);
#pragma unroll
    for (int j = 0; j < 2; ++j)
      bb[j] = *reinterpret_cast<const short8v*>(&TB[wn * 32 + j * 16 + (l & 15)][ks * 32 + (l >> 4) * 8]);
#pragma unroll
    for (int i = 0; i < 2; ++i)
#pragma unroll
      for (int j = 0; j < 2; ++j)
        acc[i][j] = __builtin_amdgcn_mfma_f32_16x16x32_bf16(a[i], bb[j], acc[i][j], 0, 0, 0);
  }
  // per-row reductions against c2_lw and r2
  float cw[2], rv[2], lb[2];
#pragma unroll
  for (int j = 0; j < 2; ++j) {
    int col = wn * 32 + j * 16 + (l & 15);
    cw[j] = c2_lw[col]; rv[j] = r2f[col]; lb[j] = c1_lb[col];
  }
#pragma unroll
  for (int i = 0; i < 2; ++i)
#pragma unroll
    for (int r = 0; r < 4; ++r) {
      float wp = 0.f, tp = 0.f;
#pragma unroll
      for (int j = 0; j < 2; ++j) {
        float val = fmaxf(acc[i][j][r] + lb[j], 0.0f);
        wp += val * cw[j];
        tp += val * rv[j];
      }
#pragma unroll
      for (int m = 1; m < 16; m <<= 1) {
        wp += __shfl_xor(wp, m, 64);
        tp += __shfl_xor(tp, m, 64);
      }
      if ((l & 15) == 0) {
        int rowL = wm * 32 + i * 16 + (l >> 4) * 4 + r;
        ws2[rowL][wn] = wp;
        ts2[rowL][wn] = tp;
      }
    }
  __syncthreads();
  if (t < 64) {
    w2[row0 + t]  = ws2[t][0] + ws2[t][1];
    t2v[row0 + t] = ts2[t][0] + ts2[t][1];
  }
}

// ---------------- K4: fused m2 GEMV + barrier + sigmoid output --------------------------
// grid (32, 8), 256 threads. Phase 1: wave-per-d GEMV m2[b][d]. Barrier over the 32
// blocks of batch b. Phase 2: block handles 64 rows -> out.
__global__ __launch_bounds__(256) void k_m2out(const USH* __restrict__ xnbT,
                                               const USH* __restrict__ xnb,
                                               const float* __restrict__ w2,
                                               const float* __restrict__ t2v,
                                               const float* __restrict__ c2_lb,
                                               const float* __restrict__ mask,
                                               float* __restrict__ m2f,
                                               float* __restrict__ out,
                                               unsigned* __restrict__ ctr2) {
  __shared__ float m2s[128];
  const int t = threadIdx.x;
  const int w = t >> 6, l = t & 63;
  const int c = blockIdx.x, b = blockIdx.y;

  // ---- phase 1: m2[b][d] for d = c*4 + w ----
  {
    const int d = c * 4 + w;
    const USH* xr = xnbT + ((size_t)b * D1 + d) * NN;
    const float* wr = w2 + (size_t)b * NN;
    float s = 0.f;
#pragma unroll
    for (int pass = 0; pass < 4; ++pass) {
      int n0 = pass * 512 + l * 8;
      short8v xv = *reinterpret_cast<const short8v*>(&xr[n0]);
      float4 wa = *reinterpret_cast<const float4*>(&wr[n0]);
      float4 wb = *reinterpret_cast<const float4*>(&wr[n0 + 4]);
      s += bf2f((USH)xv[0]) * wa.x + bf2f((USH)xv[1]) * wa.y
         + bf2f((USH)xv[2]) * wa.z + bf2f((USH)xv[3]) * wa.w
         + bf2f((USH)xv[4]) * wb.x + bf2f((USH)xv[5]) * wb.y
         + bf2f((USH)xv[6]) * wb.z + bf2f((USH)xv[7]) * wb.w;
    }
#pragma unroll
    for (int m = 1; m < 64; m <<= 1) s += __shfl_xor(s, m, 64);
    if (l == 0) m2f[b * D1 + d] = s * (1.0f / 2047.0f);
  }

  // ---- barrier across 32 blocks of batch b ----
  batch_barrier(&ctr2[b], 32u);

  // ---- phase 2: out for rows b*2048 + c*64 .. +63 ----
  if (t < 128) m2s[t] = m2f[b * D1 + t];
  __syncthreads();
  const float cb = c2_lb[0];
  const int rbase = b * NN + c * 64 + w * 16;
#pragma unroll
  for (int rr = 0; rr < 16; ++rr) {
    int row = rbase + rr;
    float s = bf2f(xnb[(size_t)row * D1 + l]) * m2s[l]
            + bf2f(xnb[(size_t)row * D1 + 64 + l]) * m2s[64 + l];
#pragma unroll
    for (int m = 1; m < 64; m <<= 1) s += __shfl_xor(s, m, 64);
    if (l == 0) {
      float v = s + t2v[row] + cb;
      out[row] = (1.0f / (1.0f + expf(-v))) * mask[row];
    }
  }
}

extern "C" void kernel_launch(void* const* d_in, const int* in_sizes, int n_in,
                              void* d_out, int out_size, void* d_ws, size_t ws_size,
                              hipStream_t stream) {
  const float* x      = (const float*)d_in[0];
  const float* mask   = (const float*)d_in[1];
  const float* w1     = (const float*)d_in[2];
  const float* b1     = (const float*)d_in[3];
  const float* c1_lw  = (const float*)d_in[4];
  const float* c1_lb  = (const float*)d_in[5];
  const float* c1_rw  = (const float*)d_in[6];
  const float* c2_lw  = (const float*)d_in[7];
  const float* c2_lb  = (const float*)d_in[8];
  const float* c2_rw  = (const float*)d_in[9];
  float* ws  = (float*)d_ws;
  USH* xnb   = (USH*)(ws + OFF_XNB);
  USH* xnbT  = (USH*)(ws + OFF_XNBT);
  float* nrm = ws + OFF_NRM;
  float* w2  = ws + OFF_W2;
  float* t2v = ws + OFF_T2V;
  float* P1  = ws + OFF_P1;
  USH* M1T   = (USH*)(ws + OFF_M1T);
  USH* R1T   = (USH*)(ws + OFF_R1T);
  float* m2f = ws + OFF_M2F;
  float* r2f = ws + OFF_R2F;
  unsigned* ctr = (unsigned*)(ws + OFF_CTR);   // [0..7] s1m1, [8..15] m2out
  USH* w1b   = (USH*)(ws + OFF_P1);  // aliases P1 (P1 written only after gemm_h done)
  float* out = (float*)d_out;

  k_prep<<<dim3(99), dim3(256), 0, stream>>>(w1, c1_lw, c1_rw, c2_lw, c2_rw, w1b, R1T, r2f, ctr);
  k_gemm_h<<<dim3(BN / 32), dim3(256), 0, stream>>>(x, w1b, b1, xnb, xnbT, nrm);
  k_s1m1<<<dim3(NCH, BB), dim3(256), 0, stream>>>(xnbT, nrm, c1_lw, P1, M1T, ctr);
  k_h1<<<dim3(BN / 64), dim3(256), 0, stream>>>(xnb, nrm, M1T, R1T, c1_lb, c2_lw, r2f, w2, t2v);
  k_m2out<<<dim3(32, BB), dim3(256), 0, stream>>>(xnbT, xnb, w2, t2v, c2_lb, mask, m2f, out, ctr + 8);
}

// Round 8
// 54.538 us; speedup vs baseline: 1.1515x; 1.1515x over previous
//
#include <hip/hip_runtime.h>
#include <hip/hip_bf16.h>
#include <math.h>

#define BB 8
#define NN 2048
#define HH 768
#define D1 128
#define D2 64
#define BN (BB*NN)            // 16384 rows total
#define NCH 8                 // split-n chunks for S1 partial reduction (2 subchunks each)
#define NSPAN (NN/NCH)        // 256 rows per chunk

// workspace offsets (floats)
#define OFF_XNB   0u          // bf16 [BN][128]
#define OFF_XNBT  1048576u    // bf16 [8][128][2048]
#define OFF_NRM   2097152u    // f32  [BN]
#define OFF_W2    2113536u    // f32  [BN]   (h1 . c2_lw per row)
#define OFF_T2V   2129920u    // f32  [BN]   (h1 . r2 per row)
#define OFF_P1    2146304u    // f32 [8][8][128][128] = 4 MB  (w1b bf16 aliases here pre-s1)
#define OFF_M1T   3194880u    // bf16 [8][64][128]
#define OFF_R1T   3227648u    // bf16 [64][128]
#define OFF_M2F   3231744u    // f32 [8][128]
#define OFF_R2F   3232768u    // f32 [64]

typedef __attribute__((ext_vector_type(8))) short short8v;
typedef __attribute__((ext_vector_type(4))) float f32x4;
typedef unsigned short USH;

__device__ __forceinline__ USH f2bf(float f) {
  unsigned int u = __builtin_bit_cast(unsigned int, f);
  u = (u + 0x7fffu + ((u >> 16) & 1u)) >> 16;
  return (USH)u;
}
__device__ __forceinline__ float bf2f(USH u) {
  return __builtin_bit_cast(float, ((unsigned int)u) << 16);
}

#define GLDS16(gp, lp)                                                        \
  __builtin_amdgcn_global_load_lds((const __attribute__((address_space(1))) void*)(gp), \
                                   (__attribute__((address_space(3))) void*)(lp), 16, 0, 0)

// ---------------- K0: prep — w1->bf16, R1T, r2 ----------------
__global__ __launch_bounds__(256) void k_prep(const float* __restrict__ w1,
                                              const float* __restrict__ c1_lw,
                                              const float* __restrict__ c1_rw,
                                              const float* __restrict__ c2_lw,
                                              const float* __restrict__ c2_rw,
                                              USH* __restrict__ w1b,
                                              USH* __restrict__ R1T,
                                              float* __restrict__ r2f) {
  const int bid = blockIdx.x, t = threadIdx.x;
  const float inv = 1.0f / 2047.0f;
  if (bid < 96) {
    int i = (bid * 256 + t) * 4;
    float4 v = *reinterpret_cast<const float4*>(&w1[i]);
    ushort4 o;
    o.x = f2bf(v.x); o.y = f2bf(v.y); o.z = f2bf(v.z); o.w = f2bf(v.w);
    *reinterpret_cast<ushort4*>(&w1b[i]) = o;
  } else if (bid < 98) {
    int base = (bid - 96) * 4096 + t * 16;
#pragma unroll
    for (int k = 0; k < 16; ++k) {
      int i = base + k;
      R1T[i] = f2bf(c1_rw[i] - c1_lw[i] * inv);
    }
  } else {
    if (t < D2) r2f[t] = c2_rw[t] - c2_lw[t] * inv;
  }
}

// ---------------- K1: h = x @ w1^T + b1 (bf16 MFMA, BM=32 BK=64, swizzled LDS) --------
// emits xnb [n][128], xnbT [b][128][2048], nrm [n]   (h == xn * nrm, never stored)
__global__ __launch_bounds__(256) void k_gemm_h(const float* __restrict__ x,
                                                const USH* __restrict__ w1b,
                                                const float* __restrict__ b1,
                                                USH* __restrict__ xnb,
                                                USH* __restrict__ xnbT,
                                                float* __restrict__ nrm) {
  __shared__ __align__(16) USH As[2][32][64];   // 8 KB  (slot-swizzled)
  __shared__ __align__(16) USH Bs[2][128][64];  // 32 KB (slot-swizzled)
  __shared__ float norms[32][2];
  __shared__ __align__(16) USH T[128][40];      // 10 KB transpose buffer

  const int t = threadIdx.x;
  const int w = t >> 6, l = t & 63;
  const int wm = w & 1, wn = w >> 1;
  const int row0 = blockIdx.x * 32;
  const int b_ = row0 >> 11, nloc = row0 & (NN - 1);

  const int arow = t >> 3, aseg = t & 7;
  const int aslot = aseg ^ (arow & 7);
  const size_t xbase = (size_t)(row0 + arow) * HH;
  const int brow_l = w * 32 + (l >> 3);

  f32x4 acc[4] = {};

  {  // prologue: buffer 0
#pragma unroll
    for (int q = 0; q < 4; ++q) {
      int brow = brow_l + q * 8;
      int gslot = (l & 7) ^ (brow & 7);
      GLDS16(w1b + (size_t)brow * HH + gslot * 8, &Bs[0][w * 32 + q * 8][0]);
    }
    float4 xa = *reinterpret_cast<const float4*>(&x[xbase + aseg * 8]);
    float4 xb = *reinterpret_cast<const float4*>(&x[xbase + aseg * 8 + 4]);
    short8v v;
    v[0] = (short)f2bf(xa.x); v[1] = (short)f2bf(xa.y);
    v[2] = (short)f2bf(xa.z); v[3] = (short)f2bf(xa.w);
    v[4] = (short)f2bf(xb.x); v[5] = (short)f2bf(xb.y);
    v[6] = (short)f2bf(xb.z); v[7] = (short)f2bf(xb.w);
    *reinterpret_cast<short8v*>(&As[0][arow][aslot * 8]) = v;
  }

  for (int kt = 0; kt < HH / 64; ++kt) {
    const int cur = kt & 1, nxt = cur ^ 1;
    __syncthreads();

    float4 xa, xb;
    if (kt < HH / 64 - 1) {
      const int k0n = (kt + 1) * 64;
#pragma unroll
      for (int q = 0; q < 4; ++q) {
        int brow = brow_l + q * 8;
        int gslot = (l & 7) ^ (brow & 7);
        GLDS16(w1b + (size_t)brow * HH + k0n + gslot * 8, &Bs[nxt][w * 32 + q * 8][0]);
      }
      xa = *reinterpret_cast<const float4*>(&x[xbase + k0n + aseg * 8]);
      xb = *reinterpret_cast<const float4*>(&x[xbase + k0n + aseg * 8 + 4]);
    }

    const int ar = wm * 16 + (l & 15);
#pragma unroll
    for (int ks = 0; ks < 2; ++ks) {
      short8v a = *reinterpret_cast<const short8v*>(
          &As[cur][ar][((ks * 4 + (l >> 4)) ^ (ar & 7)) * 8]);
#pragma unroll
      for (int ni = 0; ni < 4; ++ni) {
        int br = wn * 64 + ni * 16 + (l & 15);
        short8v b = *reinterpret_cast<const short8v*>(
            &Bs[cur][br][((ks * 4 + (l >> 4)) ^ (br & 7)) * 8]);
        acc[ni] = __builtin_amdgcn_mfma_f32_16x16x32_bf16(a, b, acc[ni], 0, 0, 0);
      }
    }

    if (kt < HH / 64 - 1) {
      short8v v;
      v[0] = (short)f2bf(xa.x); v[1] = (short)f2bf(xa.y);
      v[2] = (short)f2bf(xa.z); v[3] = (short)f2bf(xa.w);
      v[4] = (short)f2bf(xb.x); v[5] = (short)f2bf(xb.y);
      v[6] = (short)f2bf(xb.z); v[7] = (short)f2bf(xb.w);
      *reinterpret_cast<short8v*>(&As[nxt][arow][aslot * 8]) = v;
    }
  }

  // epilogue: bias, row-norm, write xnb + xnbT + nrm
  float bv[4];
#pragma unroll
  for (int ni = 0; ni < 4; ++ni) bv[ni] = b1[wn * 64 + ni * 16 + (l & 15)];
#pragma unroll
  for (int ni = 0; ni < 4; ++ni)
#pragma unroll
    for (int r = 0; r < 4; ++r) acc[ni][r] += bv[ni];

#pragma unroll
  for (int r = 0; r < 4; ++r) {
    float s = 0.f;
#pragma unroll
    for (int ni = 0; ni < 4; ++ni) { float v = acc[ni][r]; s += v * v; }
#pragma unroll
    for (int m = 1; m < 16; m <<= 1) s += __shfl_xor(s, m, 64);
    if ((l & 15) == 0) norms[wm * 16 + (l >> 4) * 4 + r][wn] = s;
  }
  __syncthreads();

#pragma unroll
  for (int r = 0; r < 4; ++r) {
    int row = wm * 16 + (l >> 4) * 4 + r;
    float tot = norms[row][0] + norms[row][1];
    float ncl = fmaxf(sqrtf(tot), 1e-8f);
    float inv = 1.0f / ncl;
    if (wn == 0 && (l & 15) == 0) nrm[row0 + row] = ncl;
    size_t gbase = (size_t)(row0 + row) * D1;
#pragma unroll
    for (int ni = 0; ni < 4; ++ni) {
      int col = wn * 64 + ni * 16 + (l & 15);
      USH xv = f2bf(acc[ni][r] * inv);
      xnb[gbase + col] = xv;
      T[col][row] = xv;
    }
  }
  __syncthreads();
  {
    int d = t >> 1, seg = t & 1;
    size_t g = ((size_t)b_ * D1 + d) * NN + nloc + seg * 16;
    *reinterpret_cast<short8v*>(&xnbT[g]) =
        *reinterpret_cast<const short8v*>(&T[d][seg * 16]);
    *reinterpret_cast<short8v*>(&xnbT[g + 8]) =
        *reinterpret_cast<const short8v*>(&T[d][seg * 16 + 8]);
  }
}

// ---------------- K2: S1 partials = xnT(chunk) @ (diag(nrm) xn)(chunk) via MFMA --------
// grid (8 ch, 8 b); each block accumulates TWO 128-row subchunks (n-span 256) in regs.
__global__ __launch_bounds__(256) void k_s1(const USH* __restrict__ xnbT,
                                            const float* __restrict__ nrm,
                                            float* __restrict__ P1) {
  __shared__ __align__(16) short TA[128][136];
  __shared__ __align__(16) short TB[128][136];
  const int t = threadIdx.x;
  const int ch = blockIdx.x, b = blockIdx.y;
  const int w = t >> 6, l = t & 63;
  const int wm = w & 1, wn = w >> 1;
  f32x4 acc[4][4] = {};

  for (int sc = 0; sc < 2; ++sc) {
    const int n0 = ch * NSPAN + sc * 128;
    {
      const int r0 = t >> 4;
      const int c8 = (t & 15) * 8;
      float4 nva = *reinterpret_cast<const float4*>(&nrm[(size_t)b * NN + n0 + c8]);
      float4 nvb = *reinterpret_cast<const float4*>(&nrm[(size_t)b * NN + n0 + c8 + 4]);
      float nv[8] = {nva.x, nva.y, nva.z, nva.w, nvb.x, nvb.y, nvb.z, nvb.w};
#pragma unroll
      for (int p = 0; p < 8; ++p) {
        int row = p * 16 + r0;
        short8v v = *reinterpret_cast<const short8v*>(&xnbT[((size_t)b * D1 + row) * NN + n0 + c8]);
        *reinterpret_cast<short8v*>(&TA[row][c8]) = v;
        short8v hv;
#pragma unroll
        for (int j = 0; j < 8; ++j) hv[j] = (short)f2bf(bf2f((USH)v[j]) * nv[j]);
        *reinterpret_cast<short8v*>(&TB[row][c8]) = hv;
      }
    }
    __syncthreads();
#pragma unroll
    for (int ks = 0; ks < 4; ++ks) {
      short8v a[4], bb[4];
#pragma unroll
      for (int fi = 0; fi < 4; ++fi)
        a[fi] = *reinterpret_cast<const short8v*>(&TA[wm * 64 + fi * 16 + (l & 15)][ks * 32 + (l >> 4) * 8]);
#pragma unroll
      for (int fj = 0; fj < 4; ++fj)
        bb[fj] = *reinterpret_cast<const short8v*>(&TB[wn * 64 + fj * 16 + (l & 15)][ks * 32 + (l >> 4) * 8]);
#pragma unroll
      for (int fi = 0; fi < 4; ++fi)
#pragma unroll
        for (int fj = 0; fj < 4; ++fj)
          acc[fi][fj] = __builtin_amdgcn_mfma_f32_16x16x32_bf16(a[fi], bb[fj], acc[fi][fj], 0, 0, 0);
    }
    __syncthreads();   // safe to overwrite TA/TB next subchunk
  }

  float* P = P1 + ((size_t)b * NCH + ch) * (D1 * D1);
#pragma unroll
  for (int fi = 0; fi < 4; ++fi)
#pragma unroll
    for (int fj = 0; fj < 4; ++fj)
#pragma unroll
      for (int r = 0; r < 4; ++r) {
        int row = wm * 64 + fi * 16 + (l >> 4) * 4 + r;
        int col = wn * 64 + fj * 16 + (l & 15);
        P[(size_t)row * D1 + col] = acc[fi][fj][r];
      }
}

// ---------------- K3: fused reduce(P1) + M1T = (S1@c1_lw^T/2047)^T (bf16) --------------
// grid (16 d-chunks of 8 rows, 8 b), 256 threads
__global__ __launch_bounds__(256) void k_m1_fused(const float* __restrict__ P1,
                                                  const float* __restrict__ c1_lw,
                                                  USH* __restrict__ M1T) {
  __shared__ float s_s[8][128];     // 4 KB
  __shared__ float lw_s[64][132];   // 33.8 KB
  const int t = threadIdx.x;
  const int dchunk = blockIdx.x;    // rows dchunk*8 .. +7
  const int b = blockIdx.y;
  const float inv = 1.0f / 2047.0f;

#pragma unroll
  for (int q = 0; q < 8; ++q) {
    int idx4 = q * 256 + t;
    int o = idx4 >> 5, e4 = idx4 & 31;
    float4 v = *reinterpret_cast<const float4*>(&c1_lw[o * 128 + e4 * 4]);
    *reinterpret_cast<float4*>(&lw_s[o][e4 * 4]) = v;
  }
  const float* Pb = P1 + (size_t)b * NCH * (D1 * D1) + (size_t)(dchunk * 8) * D1;
  {
    int r = t >> 5, e4 = t & 31;
    float4 s = make_float4(0.f, 0.f, 0.f, 0.f);
#pragma unroll
    for (int c = 0; c < NCH; ++c) {
      float4 v = *reinterpret_cast<const float4*>(&Pb[(size_t)c * (D1 * D1) + r * D1 + e4 * 4]);
      s.x += v.x; s.y += v.y; s.z += v.z; s.w += v.w;
    }
    *reinterpret_cast<float4*>(&s_s[r][e4 * 4]) = s;
  }
  __syncthreads();

  const int row = t >> 5;           // 0..7
  const int ox = t & 31;            // o and o+32
  float a0 = 0.f, a1 = 0.f;
  for (int e4 = 0; e4 < 32; ++e4) {
    float4 lw0 = *reinterpret_cast<const float4*>(&lw_s[ox][e4 * 4]);
    float4 lw1 = *reinterpret_cast<const float4*>(&lw_s[ox + 32][e4 * 4]);
    float4 sv = *reinterpret_cast<const float4*>(&s_s[row][e4 * 4]);
    a0 += sv.x * lw0.x + sv.y * lw0.y + sv.z * lw0.z + sv.w * lw0.w;
    a1 += sv.x * lw1.x + sv.y * lw1.y + sv.z * lw1.z + sv.w * lw1.w;
  }
  int d = dchunk * 8 + row;
  M1T[((size_t)b * D2 + ox) * D1 + d]      = f2bf(a0 * inv);
  M1T[((size_t)b * D2 + ox + 32) * D1 + d] = f2bf(a1 * inv);
}

// ---------------- K4: h1 = relu([xn | nrm*xn] @ [M1T|R1T]^T + c1_lb) (K=256 MFMA) ------
// epilogue reduces h1 rows against c2_lw and r2 -> w2[n], t2[n] (fp32). No h1 stored.
__global__ __launch_bounds__(256) void k_h1(const USH* __restrict__ xnb,
                                            const float* __restrict__ nrm,
                                            const USH* __restrict__ M1T,
                                            const USH* __restrict__ R1T,
                                            const float* __restrict__ c1_lb,
                                            const float* __restrict__ c2_lw,
                                            const float* __restrict__ r2f,
                                            float* __restrict__ w2,
                                            float* __restrict__ t2v) {
  __shared__ __align__(16) short TA[64][280];
  __shared__ __align__(16) short TB[64][280];
  __shared__ float ws2[64][2], ts2[64][2];
  const int t = threadIdx.x;
  const int row0 = blockIdx.x * 64;
  const int b = row0 >> 11;
  {
    const int row = t >> 2, seg = t & 3;
    const float nr = nrm[row0 + row];
#pragma unroll
    for (int j = 0; j < 4; ++j) {
      int e = seg * 32 + j * 8;
      short8v v = *reinterpret_cast<const short8v*>(&xnb[(size_t)(row0 + row) * D1 + e]);
      *reinterpret_cast<short8v*>(&TA[row][e]) = v;
      short8v sv;
#pragma unroll
      for (int jj = 0; jj < 8; ++jj) sv[jj] = (short)f2bf(bf2f((USH)v[jj]) * nr);
      *reinterpret_cast<short8v*>(&TA[row][128 + e]) = sv;
      *reinterpret_cast<short8v*>(&TB[row][e]) =
          *reinterpret_cast<const short8v*>(&M1T[((size_t)b * D2 + row) * D1 + e]);
      *reinterpret_cast<short8v*>(&TB[row][128 + e]) =
          *reinterpret_cast<const short8v*>(&R1T[(size_t)row * D1 + e]);
    }
  }
  __syncthreads();
  const int w = t >> 6, l = t & 63;
  const int wm = w & 1, wn = w >> 1;
  f32x4 acc[2][2] = {};
#pragma unroll
  for (int ks = 0; ks < 8; ++ks) {
    short8v a[2], bb[2];
#pragma unroll
    for (int i = 0; i < 2; ++i)
      a[i] = *reinterpret_cast<const short8v*>(&TA[wm * 32 + i * 16 + (l & 15)][ks * 32 + (l >> 4) * 8]);
#pragma unroll
    for (int j = 0; j < 2; ++j)
      bb[j] = *reinterpret_cast<const short8v*>(&TB[wn * 32 + j * 16 + (l & 15)][ks * 32 + (l >> 4) * 8]);
#pragma unroll
    for (int i = 0; i < 2; ++i)
#pragma unroll
      for (int j = 0; j < 2; ++j)
        acc[i][j] = __builtin_amdgcn_mfma_f32_16x16x32_bf16(a[i], bb[j], acc[i][j], 0, 0, 0);
  }
  // per-row reductions against c2_lw and r2
  float cw[2], rv[2], lb[2];
#pragma unroll
  for (int j = 0; j < 2; ++j) {
    int col = wn * 32 + j * 16 + (l & 15);
    cw[j] = c2_lw[col]; rv[j] = r2f[col]; lb[j] = c1_lb[col];
  }
#pragma unroll
  for (int i = 0; i < 2; ++i)
#pragma unroll
    for (int r = 0; r < 4; ++r) {
      float wp = 0.f, tp = 0.f;
#pragma unroll
      for (int j = 0; j < 2; ++j) {
        float val = fmaxf(acc[i][j][r] + lb[j], 0.0f);
        wp += val * cw[j];
        tp += val * rv[j];
      }
#pragma unroll
      for (int m = 1; m < 16; m <<= 1) {
        wp += __shfl_xor(wp, m, 64);
        tp += __shfl_xor(tp, m, 64);
      }
      if ((l & 15) == 0) {
        int rowL = wm * 32 + i * 16 + (l >> 4) * 4 + r;
        ws2[rowL][wn] = wp;
        ts2[rowL][wn] = tp;
      }
    }
  __syncthreads();
  if (t < 64) {
    w2[row0 + t]  = ws2[t][0] + ws2[t][1];
    t2v[row0 + t] = ts2[t][0] + ts2[t][1];
  }
}

// ---------------- K5: m2[b][d] = (sum_n xnbT[b][d][n] * w2[b][n]) / 2047 (GEMV) --------
// grid (32, 8), 4 waves; wave handles one d-row
__global__ __launch_bounds__(256) void k_m2(const USH* __restrict__ xnbT,
                                            const float* __restrict__ w2,
                                            float* __restrict__ m2f) {
  const int t = threadIdx.x;
  const int w = t >> 6, l = t & 63;
  const int b = blockIdx.y;
  const int d = blockIdx.x * 4 + w;
  const USH* xr = xnbT + ((size_t)b * D1 + d) * NN;
  const float* wr = w2 + (size_t)b * NN;
  float s = 0.f;
#pragma unroll
  for (int pass = 0; pass < 4; ++pass) {
    int n0 = pass * 512 + l * 8;
    short8v xv = *reinterpret_cast<const short8v*>(&xr[n0]);
    float4 wa = *reinterpret_cast<const float4*>(&wr[n0]);
    float4 wb = *reinterpret_cast<const float4*>(&wr[n0 + 4]);
    s += bf2f((USH)xv[0]) * wa.x + bf2f((USH)xv[1]) * wa.y
       + bf2f((USH)xv[2]) * wa.z + bf2f((USH)xv[3]) * wa.w
       + bf2f((USH)xv[4]) * wb.x + bf2f((USH)xv[5]) * wb.y
       + bf2f((USH)xv[6]) * wb.z + bf2f((USH)xv[7]) * wb.w;
  }
#pragma unroll
  for (int m = 1; m < 64; m <<= 1) s += __shfl_xor(s, m, 64);
  if (l == 0) m2f[b * D1 + d] = s * (1.0f / 2047.0f);
}

// ---------------- K6: out = sigmoid(xnb.m2 + t2 + c2_lb) * mask ----------------
__global__ __launch_bounds__(256) void k_out(const USH* __restrict__ xnb,
                                             const float* __restrict__ m2f,
                                             const float* __restrict__ t2v,
                                             const float* __restrict__ c2_lb,
                                             const float* __restrict__ mask,
                                             float* __restrict__ out) {
  int row = blockIdx.x * 4 + (threadIdx.x >> 6);
  int lane = threadIdx.x & 63;
  int b = row >> 11;
  float s = bf2f(xnb[(size_t)row * D1 + lane]) * m2f[b * D1 + lane]
          + bf2f(xnb[(size_t)row * D1 + 64 + lane]) * m2f[b * D1 + 64 + lane];
#pragma unroll
  for (int m = 1; m < 64; m <<= 1) s += __shfl_xor(s, m, 64);
  if (lane == 0) {
    float v = s + t2v[row] + c2_lb[0];
    out[row] = (1.0f / (1.0f + expf(-v))) * mask[row];
  }
}

extern "C" void kernel_launch(void* const* d_in, const int* in_sizes, int n_in,
                              void* d_out, int out_size, void* d_ws, size_t ws_size,
                              hipStream_t stream) {
  const float* x      = (const float*)d_in[0];
  const float* mask   = (const float*)d_in[1];
  const float* w1     = (const float*)d_in[2];
  const float* b1     = (const float*)d_in[3];
  const float* c1_lw  = (const float*)d_in[4];
  const float* c1_lb  = (const float*)d_in[5];
  const float* c1_rw  = (const float*)d_in[6];
  const float* c2_lw  = (const float*)d_in[7];
  const float* c2_lb  = (const float*)d_in[8];
  const float* c2_rw  = (const float*)d_in[9];
  float* ws  = (float*)d_ws;
  USH* xnb   = (USH*)(ws + OFF_XNB);
  USH* xnbT  = (USH*)(ws + OFF_XNBT);
  float* nrm = ws + OFF_NRM;
  float* w2  = ws + OFF_W2;
  float* t2v = ws + OFF_T2V;
  float* P1  = ws + OFF_P1;
  USH* M1T   = (USH*)(ws + OFF_M1T);
  USH* R1T   = (USH*)(ws + OFF_R1T);
  float* m2f = ws + OFF_M2F;
  float* r2f = ws + OFF_R2F;
  USH* w1b   = (USH*)(ws + OFF_P1);  // aliases P1 (P1 written only after gemm_h done)
  float* out = (float*)d_out;

  k_prep<<<dim3(99), dim3(256), 0, stream>>>(w1, c1_lw, c1_rw, c2_lw, c2_rw, w1b, R1T, r2f);
  k_gemm_h<<<dim3(BN / 32), dim3(256), 0, stream>>>(x, w1b, b1, xnb, xnbT, nrm);
  k_s1<<<dim3(NCH, BB), dim3(256), 0, stream>>>(xnbT, nrm, P1);
  k_m1_fused<<<dim3(16, BB), dim3(256), 0, stream>>>(P1, c1_lw, M1T);
  k_h1<<<dim3(BN / 64), dim3(256), 0, stream>>>(xnb, nrm, M1T, R1T, c1_lb, c2_lw, r2f, w2, t2v);
  k_m2<<<dim3(32, BB), dim3(256), 0, stream>>>(xnbT, w2, m2f);
  k_out<<<dim3(BN / 4), dim3(256), 0, stream>>>(xnb, m2f, t2v, c2_lb, mask, out);
}

// Round 9
// 51.956 us; speedup vs baseline: 1.2087x; 1.0497x over previous
//
#include <hip/hip_runtime.h>
#include <hip/hip_bf16.h>
#include <math.h>

#define BB 8
#define NN 2048
#define HH 768
#define D1 128
#define D2 64
#define BN (BB*NN)            // 16384 rows total
#define NCH 16                // split-n chunks for S1 partial reduction
#define ROWS_PER_CH (NN/NCH)  // 128

// workspace offsets (floats)
#define OFF_XNB   0u          // bf16 [BN][128]
#define OFF_XNBT  1048576u    // bf16 [8][128][2048]
#define OFF_NRM   2097152u    // f32  [BN]
#define OFF_W2    2113536u    // f32  [BN]   (h1 . c2_lw per row)
#define OFF_T2V   2129920u    // f32  [BN]   (h1 . r2 per row)
#define OFF_P1    2146304u    // f32 [8][16][128][128]  (w1b bf16 aliases here pre-s1)
#define OFF_M1T   4243456u    // bf16 [8][64][128]
#define OFF_R1T   4276224u    // bf16 [64][128]
#define OFF_P2M   4280320u    // f32 [8][32][128]  (per-64-row-block partial m2)
#define OFF_R2F   4313088u    // f32 [64]

typedef __attribute__((ext_vector_type(8))) short short8v;
typedef __attribute__((ext_vector_type(4))) float f32x4;
typedef unsigned short USH;

__device__ __forceinline__ USH f2bf(float f) {
  unsigned int u = __builtin_bit_cast(unsigned int, f);
  u = (u + 0x7fffu + ((u >> 16) & 1u)) >> 16;
  return (USH)u;
}
__device__ __forceinline__ float bf2f(USH u) {
  return __builtin_bit_cast(float, ((unsigned int)u) << 16);
}

#define GLDS16(gp, lp)                                                        \
  __builtin_amdgcn_global_load_lds((const __attribute__((address_space(1))) void*)(gp), \
                                   (__attribute__((address_space(3))) void*)(lp), 16, 0, 0)

// ---------------- K0: prep — w1->bf16, R1T, r2 ----------------
__global__ __launch_bounds__(256) void k_prep(const float* __restrict__ w1,
                                              const float* __restrict__ c1_lw,
                                              const float* __restrict__ c1_rw,
                                              const float* __restrict__ c2_lw,
                                              const float* __restrict__ c2_rw,
                                              USH* __restrict__ w1b,
                                              USH* __restrict__ R1T,
                                              float* __restrict__ r2f) {
  const int bid = blockIdx.x, t = threadIdx.x;
  const float inv = 1.0f / 2047.0f;
  if (bid < 96) {
    int i = (bid * 256 + t) * 4;
    float4 v = *reinterpret_cast<const float4*>(&w1[i]);
    ushort4 o;
    o.x = f2bf(v.x); o.y = f2bf(v.y); o.z = f2bf(v.z); o.w = f2bf(v.w);
    *reinterpret_cast<ushort4*>(&w1b[i]) = o;
  } else if (bid < 98) {
    int base = (bid - 96) * 4096 + t * 16;
#pragma unroll
    for (int k = 0; k < 16; ++k) {
      int i = base + k;
      R1T[i] = f2bf(c1_rw[i] - c1_lw[i] * inv);
    }
  } else {
    if (t < D2) r2f[t] = c2_rw[t] - c2_lw[t] * inv;
  }
}

// ---------------- K1: h = x @ w1^T + b1 (bf16 MFMA, BM=32 BK=64, swizzled LDS) --------
// emits xnb [n][128], xnbT [b][128][2048], nrm [n]   (h == xn * nrm, never stored)
__global__ __launch_bounds__(256) void k_gemm_h(const float* __restrict__ x,
                                                const USH* __restrict__ w1b,
                                                const float* __restrict__ b1,
                                                USH* __restrict__ xnb,
                                                USH* __restrict__ xnbT,
                                                float* __restrict__ nrm) {
  __shared__ __align__(16) USH As[2][32][64];   // 8 KB  (slot-swizzled)
  __shared__ __align__(16) USH Bs[2][128][64];  // 32 KB (slot-swizzled)
  __shared__ float norms[32][2];
  __shared__ __align__(16) USH T[128][40];      // 10 KB transpose buffer

  const int t = threadIdx.x;
  const int w = t >> 6, l = t & 63;
  const int wm = w & 1, wn = w >> 1;
  const int row0 = blockIdx.x * 32;
  const int b_ = row0 >> 11, nloc = row0 & (NN - 1);

  const int arow = t >> 3, aseg = t & 7;
  const int aslot = aseg ^ (arow & 7);
  const size_t xbase = (size_t)(row0 + arow) * HH;
  const int brow_l = w * 32 + (l >> 3);

  f32x4 acc[4] = {};

  {  // prologue: buffer 0
#pragma unroll
    for (int q = 0; q < 4; ++q) {
      int brow = brow_l + q * 8;
      int gslot = (l & 7) ^ (brow & 7);
      GLDS16(w1b + (size_t)brow * HH + gslot * 8, &Bs[0][w * 32 + q * 8][0]);
    }
    float4 xa = *reinterpret_cast<const float4*>(&x[xbase + aseg * 8]);
    float4 xb = *reinterpret_cast<const float4*>(&x[xbase + aseg * 8 + 4]);
    short8v v;
    v[0] = (short)f2bf(xa.x); v[1] = (short)f2bf(xa.y);
    v[2] = (short)f2bf(xa.z); v[3] = (short)f2bf(xa.w);
    v[4] = (short)f2bf(xb.x); v[5] = (short)f2bf(xb.y);
    v[6] = (short)f2bf(xb.z); v[7] = (short)f2bf(xb.w);
    *reinterpret_cast<short8v*>(&As[0][arow][aslot * 8]) = v;
  }

  for (int kt = 0; kt < HH / 64; ++kt) {
    const int cur = kt & 1, nxt = cur ^ 1;
    __syncthreads();

    float4 xa, xb;
    if (kt < HH / 64 - 1) {
      const int k0n = (kt + 1) * 64;
#pragma unroll
      for (int q = 0; q < 4; ++q) {
        int brow = brow_l + q * 8;
        int gslot = (l & 7) ^ (brow & 7);
        GLDS16(w1b + (size_t)brow * HH + k0n + gslot * 8, &Bs[nxt][w * 32 + q * 8][0]);
      }
      xa = *reinterpret_cast<const float4*>(&x[xbase + k0n + aseg * 8]);
      xb = *reinterpret_cast<const float4*>(&x[xbase + k0n + aseg * 8 + 4]);
    }

    const int ar = wm * 16 + (l & 15);
#pragma unroll
    for (int ks = 0; ks < 2; ++ks) {
      short8v a = *reinterpret_cast<const short8v*>(
          &As[cur][ar][((ks * 4 + (l >> 4)) ^ (ar & 7)) * 8]);
#pragma unroll
      for (int ni = 0; ni < 4; ++ni) {
        int br = wn * 64 + ni * 16 + (l & 15);
        short8v b = *reinterpret_cast<const short8v*>(
            &Bs[cur][br][((ks * 4 + (l >> 4)) ^ (br & 7)) * 8]);
        acc[ni] = __builtin_amdgcn_mfma_f32_16x16x32_bf16(a, b, acc[ni], 0, 0, 0);
      }
    }

    if (kt < HH / 64 - 1) {
      short8v v;
      v[0] = (short)f2bf(xa.x); v[1] = (short)f2bf(xa.y);
      v[2] = (short)f2bf(xa.z); v[3] = (short)f2bf(xa.w);
      v[4] = (short)f2bf(xb.x); v[5] = (short)f2bf(xb.y);
      v[6] = (short)f2bf(xb.z); v[7] = (short)f2bf(xb.w);
      *reinterpret_cast<short8v*>(&As[nxt][arow][aslot * 8]) = v;
    }
  }

  // epilogue: bias, row-norm, write xnb + xnbT + nrm
  float bv[4];
#pragma unroll
  for (int ni = 0; ni < 4; ++ni) bv[ni] = b1[wn * 64 + ni * 16 + (l & 15)];
#pragma unroll
  for (int ni = 0; ni < 4; ++ni)
#pragma unroll
    for (int r = 0; r < 4; ++r) acc[ni][r] += bv[ni];

#pragma unroll
  for (int r = 0; r < 4; ++r) {
    float s = 0.f;
#pragma unroll
    for (int ni = 0; ni < 4; ++ni) { float v = acc[ni][r]; s += v * v; }
#pragma unroll
    for (int m = 1; m < 16; m <<= 1) s += __shfl_xor(s, m, 64);
    if ((l & 15) == 0) norms[wm * 16 + (l >> 4) * 4 + r][wn] = s;
  }
  __syncthreads();

#pragma unroll
  for (int r = 0; r < 4; ++r) {
    int row = wm * 16 + (l >> 4) * 4 + r;
    float tot = norms[row][0] + norms[row][1];
    float ncl = fmaxf(sqrtf(tot), 1e-8f);
    float inv = 1.0f / ncl;
    if (wn == 0 && (l & 15) == 0) nrm[row0 + row] = ncl;
    size_t gbase = (size_t)(row0 + row) * D1;
#pragma unroll
    for (int ni = 0; ni < 4; ++ni) {
      int col = wn * 64 + ni * 16 + (l & 15);
      USH xv = f2bf(acc[ni][r] * inv);
      xnb[gbase + col] = xv;
      T[col][row] = xv;
    }
  }
  __syncthreads();
  {
    int d = t >> 1, seg = t & 1;
    size_t g = ((size_t)b_ * D1 + d) * NN + nloc + seg * 16;
    *reinterpret_cast<short8v*>(&xnbT[g]) =
        *reinterpret_cast<const short8v*>(&T[d][seg * 16]);
    *reinterpret_cast<short8v*>(&xnbT[g + 8]) =
        *reinterpret_cast<const short8v*>(&T[d][seg * 16 + 8]);
  }
}

// ---------------- K2: S1 partials = xnT(chunk) @ (diag(nrm) xn)(chunk) via MFMA --------
// grid (16 ch, 8 b) — NCH=16 for full parallelism (NCH=8 regressed: 64 blocks = 25% CUs)
__global__ __launch_bounds__(256) void k_s1(const USH* __restrict__ xnbT,
                                            const float* __restrict__ nrm,
                                            float* __restrict__ P1) {
  __shared__ __align__(16) short TA[128][136];
  __shared__ __align__(16) short TB[128][136];
  const int t = threadIdx.x;
  const int ch = blockIdx.x, b = blockIdx.y;
  const int n0 = ch * ROWS_PER_CH;
  {
    const int r0 = t >> 4;
    const int c8 = (t & 15) * 8;
    float4 nva = *reinterpret_cast<const float4*>(&nrm[(size_t)b * NN + n0 + c8]);
    float4 nvb = *reinterpret_cast<const float4*>(&nrm[(size_t)b * NN + n0 + c8 + 4]);
    float nv[8] = {nva.x, nva.y, nva.z, nva.w, nvb.x, nvb.y, nvb.z, nvb.w};
#pragma unroll
    for (int p = 0; p < 8; ++p) {
      int row = p * 16 + r0;
      short8v v = *reinterpret_cast<const short8v*>(&xnbT[((size_t)b * D1 + row) * NN + n0 + c8]);
      *reinterpret_cast<short8v*>(&TA[row][c8]) = v;
      short8v hv;
#pragma unroll
      for (int j = 0; j < 8; ++j) hv[j] = (short)f2bf(bf2f((USH)v[j]) * nv[j]);
      *reinterpret_cast<short8v*>(&TB[row][c8]) = hv;
    }
  }
  __syncthreads();
  const int w = t >> 6, l = t & 63;
  const int wm = w & 1, wn = w >> 1;
  f32x4 acc[4][4] = {};
#pragma unroll
  for (int ks = 0; ks < 4; ++ks) {
    short8v a[4], bb[4];
#pragma unroll
    for (int fi = 0; fi < 4; ++fi)
      a[fi] = *reinterpret_cast<const short8v*>(&TA[wm * 64 + fi * 16 + (l & 15)][ks * 32 + (l >> 4) * 8]);
#pragma unroll
    for (int fj = 0; fj < 4; ++fj)
      bb[fj] = *reinterpret_cast<const short8v*>(&TB[wn * 64 + fj * 16 + (l & 15)][ks * 32 + (l >> 4) * 8]);
#pragma unroll
    for (int fi = 0; fi < 4; ++fi)
#pragma unroll
      for (int fj = 0; fj < 4; ++fj)
        acc[fi][fj] = __builtin_amdgcn_mfma_f32_16x16x32_bf16(a[fi], bb[fj], acc[fi][fj], 0, 0, 0);
  }
  float* P = P1 + ((size_t)b * NCH + ch) * (D1 * D1);
#pragma unroll
  for (int fi = 0; fi < 4; ++fi)
#pragma unroll
    for (int fj = 0; fj < 4; ++fj)
#pragma unroll
      for (int r = 0; r < 4; ++r) {
        int row = wm * 64 + fi * 16 + (l >> 4) * 4 + r;
        int col = wn * 64 + fj * 16 + (l & 15);
        P[(size_t)row * D1 + col] = acc[fi][fj][r];
      }
}

// ---------------- K3: fused reduce(P1) + M1T = (S1@c1_lw^T/2047)^T (bf16) --------------
// grid (16 d-chunks of 8 rows, 8 b), 256 threads
__global__ __launch_bounds__(256) void k_m1_fused(const float* __restrict__ P1,
                                                  const float* __restrict__ c1_lw,
                                                  USH* __restrict__ M1T) {
  __shared__ float s_s[8][128];     // 4 KB
  __shared__ float lw_s[64][132];   // 33.8 KB
  const int t = threadIdx.x;
  const int dchunk = blockIdx.x;    // rows dchunk*8 .. +7
  const int b = blockIdx.y;
  const float inv = 1.0f / 2047.0f;

#pragma unroll
  for (int q = 0; q < 8; ++q) {
    int idx4 = q * 256 + t;
    int o = idx4 >> 5, e4 = idx4 & 31;
    float4 v = *reinterpret_cast<const float4*>(&c1_lw[o * 128 + e4 * 4]);
    *reinterpret_cast<float4*>(&lw_s[o][e4 * 4]) = v;
  }
  const float* Pb = P1 + (size_t)b * NCH * (D1 * D1) + (size_t)(dchunk * 8) * D1;
  {
    int r = t >> 5, e4 = t & 31;
    float4 s = make_float4(0.f, 0.f, 0.f, 0.f);
#pragma unroll
    for (int c = 0; c < NCH; ++c) {
      float4 v = *reinterpret_cast<const float4*>(&Pb[(size_t)c * (D1 * D1) + r * D1 + e4 * 4]);
      s.x += v.x; s.y += v.y; s.z += v.z; s.w += v.w;
    }
    *reinterpret_cast<float4*>(&s_s[r][e4 * 4]) = s;
  }
  __syncthreads();

  const int row = t >> 5;           // 0..7
  const int ox = t & 31;            // o and o+32
  float a0 = 0.f, a1 = 0.f;
  for (int e4 = 0; e4 < 32; ++e4) {
    float4 lw0 = *reinterpret_cast<const float4*>(&lw_s[ox][e4 * 4]);
    float4 lw1 = *reinterpret_cast<const float4*>(&lw_s[ox + 32][e4 * 4]);
    float4 sv = *reinterpret_cast<const float4*>(&s_s[row][e4 * 4]);
    a0 += sv.x * lw0.x + sv.y * lw0.y + sv.z * lw0.z + sv.w * lw0.w;
    a1 += sv.x * lw1.x + sv.y * lw1.y + sv.z * lw1.z + sv.w * lw1.w;
  }
  int d = dchunk * 8 + row;
  M1T[((size_t)b * D2 + ox) * D1 + d]      = f2bf(a0 * inv);
  M1T[((size_t)b * D2 + ox + 32) * D1 + d] = f2bf(a1 * inv);
}

// ---------------- K4: h1 = relu([xn | nrm*xn] @ [M1T|R1T]^T + c1_lb) (K=256 MFMA) ------
// epilogue: w2[n]=h1.c2_lw, t2[n]=h1.r2, AND partial m2 for this 64-row block:
// P2m[b][cblk][d] = sum_{rows in block} xn[row][d] * w2[row]   (xn still in LDS TA)
__global__ __launch_bounds__(256) void k_h1(const USH* __restrict__ xnb,
                                            const float* __restrict__ nrm,
                                            const USH* __restrict__ M1T,
                                            const USH* __restrict__ R1T,
                                            const float* __restrict__ c1_lb,
                                            const float* __restrict__ c2_lw,
                                            const float* __restrict__ r2f,
                                            float* __restrict__ w2,
                                            float* __restrict__ t2v,
                                            float* __restrict__ P2m) {
  __shared__ __align__(16) short TA[64][280];
  __shared__ __align__(16) short TB[64][280];
  __shared__ float ws2[64][2], ts2[64][2];
  __shared__ float w2row[64];
  const int t = threadIdx.x;
  const int row0 = blockIdx.x * 64;
  const int b = row0 >> 11;
  {
    const int row = t >> 2, seg = t & 3;
    const float nr = nrm[row0 + row];
#pragma unroll
    for (int j = 0; j < 4; ++j) {
      int e = seg * 32 + j * 8;
      short8v v = *reinterpret_cast<const short8v*>(&xnb[(size_t)(row0 + row) * D1 + e]);
      *reinterpret_cast<short8v*>(&TA[row][e]) = v;
      short8v sv;
#pragma unroll
      for (int jj = 0; jj < 8; ++jj) sv[jj] = (short)f2bf(bf2f((USH)v[jj]) * nr);
      *reinterpret_cast<short8v*>(&TA[row][128 + e]) = sv;
      *reinterpret_cast<short8v*>(&TB[row][e]) =
          *reinterpret_cast<const short8v*>(&M1T[((size_t)b * D2 + row) * D1 + e]);
      *reinterpret_cast<short8v*>(&TB[row][128 + e]) =
          *reinterpret_cast<const short8v*>(&R1T[(size_t)row * D1 + e]);
    }
  }
  __syncthreads();
  const int w = t >> 6, l = t & 63;
  const int wm = w & 1, wn = w >> 1;
  f32x4 acc[2][2] = {};
#pragma unroll
  for (int ks = 0; ks < 8; ++ks) {
    short8v a[2], bb[2];
#pragma unroll
    for (int i = 0; i < 2; ++i)
      a[i] = *reinterpret_cast<const short8v*>(&TA[wm * 32 + i * 16 + (l & 15)][ks * 32 + (l >> 4) * 8]);
#pragma unroll
    for (int j = 0; j < 2; ++j)
      bb[j] = *reinterpret_cast<const short8v*>(&TB[wn * 32 + j * 16 + (l & 15)][ks * 32 + (l >> 4) * 8]);
#pragma unroll
    for (int i = 0; i < 2; ++i)
#pragma unroll
      for (int j = 0; j < 2; ++j)
        acc[i][j] = __builtin_amdgcn_mfma_f32_16x16x32_bf16(a[i], bb[j], acc[i][j], 0, 0, 0);
  }
  // per-row reductions against c2_lw and r2
  float cw[2], rv[2], lb[2];
#pragma unroll
  for (int j = 0; j < 2; ++j) {
    int col = wn * 32 + j * 16 + (l & 15);
    cw[j] = c2_lw[col]; rv[j] = r2f[col]; lb[j] = c1_lb[col];
  }
#pragma unroll
  for (int i = 0; i < 2; ++i)
#pragma unroll
    for (int r = 0; r < 4; ++r) {
      float wp = 0.f, tp = 0.f;
#pragma unroll
      for (int j = 0; j < 2; ++j) {
        float val = fmaxf(acc[i][j][r] + lb[j], 0.0f);
        wp += val * cw[j];
        tp += val * rv[j];
      }
#pragma unroll
      for (int m = 1; m < 16; m <<= 1) {
        wp += __shfl_xor(wp, m, 64);
        tp += __shfl_xor(tp, m, 64);
      }
      if ((l & 15) == 0) {
        int rowL = wm * 32 + i * 16 + (l >> 4) * 4 + r;
        ws2[rowL][wn] = wp;
        ts2[rowL][wn] = tp;
      }
    }
  __syncthreads();
  if (t < 64) {
    float wsum = ws2[t][0] + ws2[t][1];
    w2[row0 + t]  = wsum;
    t2v[row0 + t] = ts2[t][0] + ts2[t][1];
    w2row[t] = wsum;
  }
  __syncthreads();
  // partial m2: column-dot of xn (TA first half) with w2row
  if (t < 128) {
    float s = 0.f;
#pragma unroll
    for (int r = 0; r < 64; ++r) s += bf2f((USH)TA[r][t]) * w2row[r];
    int cblk = (row0 >> 6) & 31;
    P2m[((size_t)b * 32 + cblk) * D1 + t] = s;
  }
}

// ---------------- K5: out — reduce P2m -> m2 (LDS), then sigmoid rows ------------------
// grid (32, 8), 256 threads; block handles 64 rows
__global__ __launch_bounds__(256) void k_out(const USH* __restrict__ xnb,
                                             const float* __restrict__ P2m,
                                             const float* __restrict__ t2v,
                                             const float* __restrict__ c2_lb,
                                             const float* __restrict__ mask,
                                             float* __restrict__ out) {
  __shared__ float m2s[128];
  const int t = threadIdx.x;
  const int c = blockIdx.x, b = blockIdx.y;
  if (t < 128) {
    float s = 0.f;
    const float* p = P2m + (size_t)b * 32 * D1 + t;
#pragma unroll
    for (int cb = 0; cb < 32; ++cb) s += p[cb * D1];
    m2s[t] = s * (1.0f / 2047.0f);
  }
  __syncthreads();
  const int w = t >> 6, l = t & 63;
  const float cbv = c2_lb[0];
  const int rbase = b * NN + c * 64 + w * 16;
#pragma unroll
  for (int rr = 0; rr < 16; ++rr) {
    int row = rbase + rr;
    float s = bf2f(xnb[(size_t)row * D1 + l]) * m2s[l]
            + bf2f(xnb[(size_t)row * D1 + 64 + l]) * m2s[64 + l];
#pragma unroll
    for (int m = 1; m < 64; m <<= 1) s += __shfl_xor(s, m, 64);
    if (l == 0) {
      float v = s + t2v[row] + cbv;
      out[row] = (1.0f / (1.0f + expf(-v))) * mask[row];
    }
  }
}

extern "C" void kernel_launch(void* const* d_in, const int* in_sizes, int n_in,
                              void* d_out, int out_size, void* d_ws, size_t ws_size,
                              hipStream_t stream) {
  const float* x      = (const float*)d_in[0];
  const float* mask   = (const float*)d_in[1];
  const float* w1     = (const float*)d_in[2];
  const float* b1     = (const float*)d_in[3];
  const float* c1_lw  = (const float*)d_in[4];
  const float* c1_lb  = (const float*)d_in[5];
  const float* c1_rw  = (const float*)d_in[6];
  const float* c2_lw  = (const float*)d_in[7];
  const float* c2_lb  = (const float*)d_in[8];
  const float* c2_rw  = (const float*)d_in[9];
  float* ws  = (float*)d_ws;
  USH* xnb   = (USH*)(ws + OFF_XNB);
  USH* xnbT  = (USH*)(ws + OFF_XNBT);
  float* nrm = ws + OFF_NRM;
  float* w2  = ws + OFF_W2;
  float* t2v = ws + OFF_T2V;
  float* P1  = ws + OFF_P1;
  USH* M1T   = (USH*)(ws + OFF_M1T);
  USH* R1T   = (USH*)(ws + OFF_R1T);
  float* P2m = ws + OFF_P2M;
  float* r2f = ws + OFF_R2F;
  USH* w1b   = (USH*)(ws + OFF_P1);  // aliases P1 (P1 written only after gemm_h done)
  float* out = (float*)d_out;

  k_prep<<<dim3(99), dim3(256), 0, stream>>>(w1, c1_lw, c1_rw, c2_lw, c2_rw, w1b, R1T, r2f);
  k_gemm_h<<<dim3(BN / 32), dim3(256), 0, stream>>>(x, w1b, b1, xnb, xnbT, nrm);
  k_s1<<<dim3(NCH, BB), dim3(256), 0, stream>>>(xnbT, nrm, P1);
  k_m1_fused<<<dim3(16, BB), dim3(256), 0, stream>>>(P1, c1_lw, M1T);
  k_h1<<<dim3(BN / 64), dim3(256), 0, stream>>>(xnb, nrm, M1T, R1T, c1_lb, c2_lw, r2f, w2, t2v, P2m);
  k_out<<<dim3(32, BB), dim3(256), 0, stream>>>(xnb, P2m, t2v, c2_lb, mask, out);
}

// Round 10
// 45.296 us; speedup vs baseline: 1.3864x; 1.1470x over previous
//
#include <hip/hip_runtime.h>
#include <hip/hip_bf16.h>
#include <math.h>

#define BB 8
#define NN 2048
#define HH 768
#define D1 128
#define D2 64
#define BN (BB*NN)            // 16384 rows total
#define NCH 16                // split-n chunks for S1 partial reduction
#define ROWS_PER_CH (NN/NCH)  // 128

// workspace offsets (floats)
#define OFF_XNB   0u          // bf16 [BN][128]
#define OFF_XNBT  1048576u    // bf16 [8][128][2048]
#define OFF_NRM   2097152u    // f32  [BN]
#define OFF_W2    2113536u    // f32  [BN]   (h1 . c2_lw per row)
#define OFF_T2V   2129920u    // f32  [BN]   (h1 . r2 per row)
#define OFF_P1    2146304u    // f32 [8][16][128][128]  (w1b bf16 aliases here pre-s1)
#define OFF_M1T   4243456u    // bf16 [8][64][128]
#define OFF_R1T   4276224u    // bf16 [64][128]
#define OFF_M2F   4280320u    // f32 [8][128]
#define OFF_R2F   4281344u    // f32 [64]

typedef __attribute__((ext_vector_type(8))) short short8v;
typedef __attribute__((ext_vector_type(4))) float f32x4;
typedef unsigned short USH;

__device__ __forceinline__ USH f2bf(float f) {
  unsigned int u = __builtin_bit_cast(unsigned int, f);
  u = (u + 0x7fffu + ((u >> 16) & 1u)) >> 16;
  return (USH)u;
}
__device__ __forceinline__ float bf2f(USH u) {
  return __builtin_bit_cast(float, ((unsigned int)u) << 16);
}

#define GLDS16(gp, lp)                                                        \
  __builtin_amdgcn_global_load_lds((const __attribute__((address_space(1))) void*)(gp), \
                                   (__attribute__((address_space(3))) void*)(lp), 16, 0, 0)

// ---------------- K0: prep — w1->bf16, R1T, r2 ----------------
__global__ __launch_bounds__(256) void k_prep(const float* __restrict__ w1,
                                              const float* __restrict__ c1_lw,
                                              const float* __restrict__ c1_rw,
                                              const float* __restrict__ c2_lw,
                                              const float* __restrict__ c2_rw,
                                              USH* __restrict__ w1b,
                                              USH* __restrict__ R1T,
                                              float* __restrict__ r2f) {
  const int bid = blockIdx.x, t = threadIdx.x;
  const float inv = 1.0f / 2047.0f;
  if (bid < 96) {
    int i = (bid * 256 + t) * 4;
    float4 v = *reinterpret_cast<const float4*>(&w1[i]);
    ushort4 o;
    o.x = f2bf(v.x); o.y = f2bf(v.y); o.z = f2bf(v.z); o.w = f2bf(v.w);
    *reinterpret_cast<ushort4*>(&w1b[i]) = o;
  } else if (bid < 98) {
    int base = (bid - 96) * 4096 + t * 16;
#pragma unroll
    for (int k = 0; k < 16; ++k) {
      int i = base + k;
      R1T[i] = f2bf(c1_rw[i] - c1_lw[i] * inv);
    }
  } else {
    if (t < D2) r2f[t] = c2_rw[t] - c2_lw[t] * inv;
  }
}

// ---------------- K1: h = x @ w1^T + b1 (bf16 MFMA, BM=32 BK=64, 512 threads) --------
// 8 waves (2M x 4N), wave tile 16x32 -> 16 waves/CU at 2 blocks/CU for latency hiding.
// emits xnb [n][128], xnbT [b][128][2048], nrm [n]   (h == xn * nrm, never stored)
__global__ __launch_bounds__(512) void k_gemm_h(const float* __restrict__ x,
                                                const USH* __restrict__ w1b,
                                                const float* __restrict__ b1,
                                                USH* __restrict__ xnb,
                                                USH* __restrict__ xnbT,
                                                float* __restrict__ nrm) {
  __shared__ __align__(16) USH As[2][32][64];   // 8 KB  (slot-swizzled)
  __shared__ __align__(16) USH Bs[2][128][64];  // 32 KB (slot-swizzled)
  __shared__ float norms[32][4];
  __shared__ __align__(16) USH T[128][40];      // 10 KB transpose buffer

  const int t = threadIdx.x;      // 0..511
  const int w = t >> 6, l = t & 63;
  const int wm = w & 1;           // M-half: 16 rows
  const int wn = w >> 1;          // N-quarter: 32 cols
  const int row0 = blockIdx.x * 32;
  const int b_ = row0 >> 11, nloc = row0 & (NN - 1);

  // A staging: threads 0..255 -> row t>>3, logical k-slot t&7 (8 elems); swizzled
  const int arow = (t & 255) >> 3, aseg = t & 7;
  const int aslot = aseg ^ (arow & 7);
  const size_t xbase = (size_t)(row0 + arow) * HH;
  // B staging: wave w covers rows w*16..+15 via 2 GLDS16 (8 rows each); source pre-swizzled
  const int brow_l = w * 16 + (l >> 3);

  f32x4 acc[2] = {};

  {  // prologue: buffer 0
#pragma unroll
    for (int q = 0; q < 2; ++q) {
      int brow = brow_l + q * 8;
      int gslot = (l & 7) ^ (brow & 7);
      GLDS16(w1b + (size_t)brow * HH + gslot * 8, &Bs[0][w * 16 + q * 8][0]);
    }
    if (t < 256) {
      float4 xa = *reinterpret_cast<const float4*>(&x[xbase + aseg * 8]);
      float4 xb = *reinterpret_cast<const float4*>(&x[xbase + aseg * 8 + 4]);
      short8v v;
      v[0] = (short)f2bf(xa.x); v[1] = (short)f2bf(xa.y);
      v[2] = (short)f2bf(xa.z); v[3] = (short)f2bf(xa.w);
      v[4] = (short)f2bf(xb.x); v[5] = (short)f2bf(xb.y);
      v[6] = (short)f2bf(xb.z); v[7] = (short)f2bf(xb.w);
      *reinterpret_cast<short8v*>(&As[0][arow][aslot * 8]) = v;
    }
  }

  for (int kt = 0; kt < HH / 64; ++kt) {
    const int cur = kt & 1, nxt = cur ^ 1;
    __syncthreads();

    float4 xa, xb;
    const bool doA = (t < 256) && (kt < HH / 64 - 1);
    if (kt < HH / 64 - 1) {
      const int k0n = (kt + 1) * 64;
#pragma unroll
      for (int q = 0; q < 2; ++q) {
        int brow = brow_l + q * 8;
        int gslot = (l & 7) ^ (brow & 7);
        GLDS16(w1b + (size_t)brow * HH + k0n + gslot * 8, &Bs[nxt][w * 16 + q * 8][0]);
      }
      if (t < 256) {
        xa = *reinterpret_cast<const float4*>(&x[xbase + k0n + aseg * 8]);
        xb = *reinterpret_cast<const float4*>(&x[xbase + k0n + aseg * 8 + 4]);
      }
    }

    const int ar = wm * 16 + (l & 15);
#pragma unroll
    for (int ks = 0; ks < 2; ++ks) {
      short8v a = *reinterpret_cast<const short8v*>(
          &As[cur][ar][((ks * 4 + (l >> 4)) ^ (ar & 7)) * 8]);
#pragma unroll
      for (int ni = 0; ni < 2; ++ni) {
        int br = wn * 32 + ni * 16 + (l & 15);
        short8v b = *reinterpret_cast<const short8v*>(
            &Bs[cur][br][((ks * 4 + (l >> 4)) ^ (br & 7)) * 8]);
        acc[ni] = __builtin_amdgcn_mfma_f32_16x16x32_bf16(a, b, acc[ni], 0, 0, 0);
      }
    }

    if (doA) {
      short8v v;
      v[0] = (short)f2bf(xa.x); v[1] = (short)f2bf(xa.y);
      v[2] = (short)f2bf(xa.z); v[3] = (short)f2bf(xa.w);
      v[4] = (short)f2bf(xb.x); v[5] = (short)f2bf(xb.y);
      v[6] = (short)f2bf(xb.z); v[7] = (short)f2bf(xb.w);
      *reinterpret_cast<short8v*>(&As[nxt][arow][aslot * 8]) = v;
    }
  }

  // epilogue: bias, row-norm, write xnb + xnbT + nrm
  float bv[2];
#pragma unroll
  for (int ni = 0; ni < 2; ++ni) bv[ni] = b1[wn * 32 + ni * 16 + (l & 15)];
#pragma unroll
  for (int ni = 0; ni < 2; ++ni)
#pragma unroll
    for (int r = 0; r < 4; ++r) acc[ni][r] += bv[ni];

#pragma unroll
  for (int r = 0; r < 4; ++r) {
    float s = 0.f;
#pragma unroll
    for (int ni = 0; ni < 2; ++ni) { float v = acc[ni][r]; s += v * v; }
#pragma unroll
    for (int m = 1; m < 16; m <<= 1) s += __shfl_xor(s, m, 64);
    if ((l & 15) == 0) norms[wm * 16 + (l >> 4) * 4 + r][wn] = s;
  }
  __syncthreads();

#pragma unroll
  for (int r = 0; r < 4; ++r) {
    int row = wm * 16 + (l >> 4) * 4 + r;
    float tot = norms[row][0] + norms[row][1] + norms[row][2] + norms[row][3];
    float ncl = fmaxf(sqrtf(tot), 1e-8f);
    float inv = 1.0f / ncl;
    if (wn == 0 && (l & 15) == 0) nrm[row0 + row] = ncl;
    size_t gbase = (size_t)(row0 + row) * D1;
#pragma unroll
    for (int ni = 0; ni < 2; ++ni) {
      int col = wn * 32 + ni * 16 + (l & 15);
      USH xv = f2bf(acc[ni][r] * inv);
      xnb[gbase + col] = xv;
      T[col][row] = xv;
    }
  }
  __syncthreads();
  {
    int d = t >> 2, seg = t & 3;
    size_t g = ((size_t)b_ * D1 + d) * NN + nloc + seg * 8;
    *reinterpret_cast<short8v*>(&xnbT[g]) =
        *reinterpret_cast<const short8v*>(&T[d][seg * 8]);
  }
}

// ---------------- K2: S1 partials = xnT(chunk) @ (diag(nrm) xn)(chunk) via MFMA --------
__global__ __launch_bounds__(256) void k_s1(const USH* __restrict__ xnbT,
                                            const float* __restrict__ nrm,
                                            float* __restrict__ P1) {
  __shared__ __align__(16) short TA[128][136];
  __shared__ __align__(16) short TB[128][136];
  const int t = threadIdx.x;
  const int ch = blockIdx.x, b = blockIdx.y;
  const int n0 = ch * ROWS_PER_CH;
  {
    const int r0 = t >> 4;
    const int c8 = (t & 15) * 8;
    float4 nva = *reinterpret_cast<const float4*>(&nrm[(size_t)b * NN + n0 + c8]);
    float4 nvb = *reinterpret_cast<const float4*>(&nrm[(size_t)b * NN + n0 + c8 + 4]);
    float nv[8] = {nva.x, nva.y, nva.z, nva.w, nvb.x, nvb.y, nvb.z, nvb.w};
#pragma unroll
    for (int p = 0; p < 8; ++p) {
      int row = p * 16 + r0;
      short8v v = *reinterpret_cast<const short8v*>(&xnbT[((size_t)b * D1 + row) * NN + n0 + c8]);
      *reinterpret_cast<short8v*>(&TA[row][c8]) = v;
      short8v hv;
#pragma unroll
      for (int j = 0; j < 8; ++j) hv[j] = (short)f2bf(bf2f((USH)v[j]) * nv[j]);
      *reinterpret_cast<short8v*>(&TB[row][c8]) = hv;
    }
  }
  __syncthreads();
  const int w = t >> 6, l = t & 63;
  const int wm = w & 1, wn = w >> 1;
  f32x4 acc[4][4] = {};
#pragma unroll
  for (int ks = 0; ks < 4; ++ks) {
    short8v a[4], bb[4];
#pragma unroll
    for (int fi = 0; fi < 4; ++fi)
      a[fi] = *reinterpret_cast<const short8v*>(&TA[wm * 64 + fi * 16 + (l & 15)][ks * 32 + (l >> 4) * 8]);
#pragma unroll
    for (int fj = 0; fj < 4; ++fj)
      bb[fj] = *reinterpret_cast<const short8v*>(&TB[wn * 64 + fj * 16 + (l & 15)][ks * 32 + (l >> 4) * 8]);
#pragma unroll
    for (int fi = 0; fi < 4; ++fi)
#pragma unroll
      for (int fj = 0; fj < 4; ++fj)
        acc[fi][fj] = __builtin_amdgcn_mfma_f32_16x16x32_bf16(a[fi], bb[fj], acc[fi][fj], 0, 0, 0);
  }
  float* P = P1 + ((size_t)b * NCH + ch) * (D1 * D1);
#pragma unroll
  for (int fi = 0; fi < 4; ++fi)
#pragma unroll
    for (int fj = 0; fj < 4; ++fj)
#pragma unroll
      for (int r = 0; r < 4; ++r) {
        int row = wm * 64 + fi * 16 + (l >> 4) * 4 + r;
        int col = wn * 64 + fj * 16 + (l & 15);
        P[(size_t)row * D1 + col] = acc[fi][fj][r];
      }
}

// ---------------- K3: fused reduce(P1) + M1T = (S1@c1_lw^T/2047)^T (bf16) --------------
__global__ __launch_bounds__(256) void k_m1_fused(const float* __restrict__ P1,
                                                  const float* __restrict__ c1_lw,
                                                  USH* __restrict__ M1T) {
  __shared__ float s_s[8][128];     // 4 KB
  __shared__ float lw_s[64][132];   // 33.8 KB
  const int t = threadIdx.x;
  const int dchunk = blockIdx.x;    // rows dchunk*8 .. +7
  const int b = blockIdx.y;
  const float inv = 1.0f / 2047.0f;

#pragma unroll
  for (int q = 0; q < 8; ++q) {
    int idx4 = q * 256 + t;
    int o = idx4 >> 5, e4 = idx4 & 31;
    float4 v = *reinterpret_cast<const float4*>(&c1_lw[o * 128 + e4 * 4]);
    *reinterpret_cast<float4*>(&lw_s[o][e4 * 4]) = v;
  }
  const float* Pb = P1 + (size_t)b * NCH * (D1 * D1) + (size_t)(dchunk * 8) * D1;
  {
    int r = t >> 5, e4 = t & 31;
    float4 s = make_float4(0.f, 0.f, 0.f, 0.f);
#pragma unroll
    for (int c = 0; c < NCH; ++c) {
      float4 v = *reinterpret_cast<const float4*>(&Pb[(size_t)c * (D1 * D1) + r * D1 + e4 * 4]);
      s.x += v.x; s.y += v.y; s.z += v.z; s.w += v.w;
    }
    *reinterpret_cast<float4*>(&s_s[r][e4 * 4]) = s;
  }
  __syncthreads();

  const int row = t >> 5;           // 0..7
  const int ox = t & 31;            // o and o+32
  float a0 = 0.f, a1 = 0.f;
  for (int e4 = 0; e4 < 32; ++e4) {
    float4 lw0 = *reinterpret_cast<const float4*>(&lw_s[ox][e4 * 4]);
    float4 lw1 = *reinterpret_cast<const float4*>(&lw_s[ox + 32][e4 * 4]);
    float4 sv = *reinterpret_cast<const float4*>(&s_s[row][e4 * 4]);
    a0 += sv.x * lw0.x + sv.y * lw0.y + sv.z * lw0.z + sv.w * lw0.w;
    a1 += sv.x * lw1.x + sv.y * lw1.y + sv.z * lw1.z + sv.w * lw1.w;
  }
  int d = dchunk * 8 + row;
  M1T[((size_t)b * D2 + ox) * D1 + d]      = f2bf(a0 * inv);
  M1T[((size_t)b * D2 + ox + 32) * D1 + d] = f2bf(a1 * inv);
}

// ---------------- K4: h1 = relu([xn | nrm*xn] @ [M1T|R1T]^T + c1_lb) (K=256 MFMA) ------
// epilogue reduces h1 rows against c2_lw and r2 -> w2[n], t2[n] (fp32). No h1 stored.
__global__ __launch_bounds__(256) void k_h1(const USH* __restrict__ xnb,
                                            const float* __restrict__ nrm,
                                            const USH* __restrict__ M1T,
                                            const USH* __restrict__ R1T,
                                            const float* __restrict__ c1_lb,
                                            const float* __restrict__ c2_lw,
                                            const float* __restrict__ r2f,
                                            float* __restrict__ w2,
                                            float* __restrict__ t2v) {
  __shared__ __align__(16) short TA[64][280];
  __shared__ __align__(16) short TB[64][280];
  __shared__ float ws2[64][2], ts2[64][2];
  const int t = threadIdx.x;
  const int row0 = blockIdx.x * 64;
  const int b = row0 >> 11;
  {
    const int row = t >> 2, seg = t & 3;
    const float nr = nrm[row0 + row];
#pragma unroll
    for (int j = 0; j < 4; ++j) {
      int e = seg * 32 + j * 8;
      short8v v = *reinterpret_cast<const short8v*>(&xnb[(size_t)(row0 + row) * D1 + e]);
      *reinterpret_cast<short8v*>(&TA[row][e]) = v;
      short8v sv;
#pragma unroll
      for (int jj = 0; jj < 8; ++jj) sv[jj] = (short)f2bf(bf2f((USH)v[jj]) * nr);
      *reinterpret_cast<short8v*>(&TA[row][128 + e]) = sv;
      *reinterpret_cast<short8v*>(&TB[row][e]) =
          *reinterpret_cast<const short8v*>(&M1T[((size_t)b * D2 + row) * D1 + e]);
      *reinterpret_cast<short8v*>(&TB[row][128 + e]) =
          *reinterpret_cast<const short8v*>(&R1T[(size_t)row * D1 + e]);
    }
  }
  __syncthreads();
  const int w = t >> 6, l = t & 63;
  const int wm = w & 1, wn = w >> 1;
  f32x4 acc[2][2] = {};
#pragma unroll
  for (int ks = 0; ks < 8; ++ks) {
    short8v a[2], bb[2];
#pragma unroll
    for (int i = 0; i < 2; ++i)
      a[i] = *reinterpret_cast<const short8v*>(&TA[wm * 32 + i * 16 + (l & 15)][ks * 32 + (l >> 4) * 8]);
#pragma unroll
    for (int j = 0; j < 2; ++j)
      bb[j] = *reinterpret_cast<const short8v*>(&TB[wn * 32 + j * 16 + (l & 15)][ks * 32 + (l >> 4) * 8]);
#pragma unroll
    for (int i = 0; i < 2; ++i)
#pragma unroll
      for (int j = 0; j < 2; ++j)
        acc[i][j] = __builtin_amdgcn_mfma_f32_16x16x32_bf16(a[i], bb[j], acc[i][j], 0, 0, 0);
  }
  // per-row reductions against c2_lw and r2
  float cw[2], rv[2], lb[2];
#pragma unroll
  for (int j = 0; j < 2; ++j) {
    int col = wn * 32 + j * 16 + (l & 15);
    cw[j] = c2_lw[col]; rv[j] = r2f[col]; lb[j] = c1_lb[col];
  }
#pragma unroll
  for (int i = 0; i < 2; ++i)
#pragma unroll
    for (int r = 0; r < 4; ++r) {
      float wp = 0.f, tp = 0.f;
#pragma unroll
      for (int j = 0; j < 2; ++j) {
        float val = fmaxf(acc[i][j][r] + lb[j], 0.0f);
        wp += val * cw[j];
        tp += val * rv[j];
      }
#pragma unroll
      for (int m = 1; m < 16; m <<= 1) {
        wp += __shfl_xor(wp, m, 64);
        tp += __shfl_xor(tp, m, 64);
      }
      if ((l & 15) == 0) {
        int rowL = wm * 32 + i * 16 + (l >> 4) * 4 + r;
        ws2[rowL][wn] = wp;
        ts2[rowL][wn] = tp;
      }
    }
  __syncthreads();
  if (t < 64) {
    w2[row0 + t]  = ws2[t][0] + ws2[t][1];
    t2v[row0 + t] = ts2[t][0] + ts2[t][1];
  }
}

// ---------------- K5: m2[b][d] = (sum_n xnbT[b][d][n] * w2[b][n]) / 2047 (GEMV) --------
__global__ __launch_bounds__(256) void k_m2(const USH* __restrict__ xnbT,
                                            const float* __restrict__ w2,
                                            float* __restrict__ m2f) {
  const int t = threadIdx.x;
  const int w = t >> 6, l = t & 63;
  const int b = blockIdx.y;
  const int d = blockIdx.x * 4 + w;
  const USH* xr = xnbT + ((size_t)b * D1 + d) * NN;
  const float* wr = w2 + (size_t)b * NN;
  float s = 0.f;
#pragma unroll
  for (int pass = 0; pass < 4; ++pass) {
    int n0 = pass * 512 + l * 8;
    short8v xv = *reinterpret_cast<const short8v*>(&xr[n0]);
    float4 wa = *reinterpret_cast<const float4*>(&wr[n0]);
    float4 wb = *reinterpret_cast<const float4*>(&wr[n0 + 4]);
    s += bf2f((USH)xv[0]) * wa.x + bf2f((USH)xv[1]) * wa.y
       + bf2f((USH)xv[2]) * wa.z + bf2f((USH)xv[3]) * wa.w
       + bf2f((USH)xv[4]) * wb.x + bf2f((USH)xv[5]) * wb.y
       + bf2f((USH)xv[6]) * wb.z + bf2f((USH)xv[7]) * wb.w;
  }
#pragma unroll
  for (int m = 1; m < 64; m <<= 1) s += __shfl_xor(s, m, 64);
  if (l == 0) m2f[b * D1 + d] = s * (1.0f / 2047.0f);
}

// ---------------- K6: out = sigmoid(xnb.m2 + t2 + c2_lb) * mask ----------------
__global__ __launch_bounds__(256) void k_out(const USH* __restrict__ xnb,
                                             const float* __restrict__ m2f,
                                             const float* __restrict__ t2v,
                                             const float* __restrict__ c2_lb,
                                             const float* __restrict__ mask,
                                             float* __restrict__ out) {
  int row = blockIdx.x * 4 + (threadIdx.x >> 6);
  int lane = threadIdx.x & 63;
  int b = row >> 11;
  float s = bf2f(xnb[(size_t)row * D1 + lane]) * m2f[b * D1 + lane]
          + bf2f(xnb[(size_t)row * D1 + 64 + lane]) * m2f[b * D1 + 64 + lane];
#pragma unroll
  for (int m = 1; m < 64; m <<= 1) s += __shfl_xor(s, m, 64);
  if (lane == 0) {
    float v = s + t2v[row] + c2_lb[0];
    out[row] = (1.0f / (1.0f + expf(-v))) * mask[row];
  }
}

extern "C" void kernel_launch(void* const* d_in, const int* in_sizes, int n_in,
                              void* d_out, int out_size, void* d_ws, size_t ws_size,
                              hipStream_t stream) {
  const float* x      = (const float*)d_in[0];
  const float* mask   = (const float*)d_in[1];
  const float* w1     = (const float*)d_in[2];
  const float* b1     = (const float*)d_in[3];
  const float* c1_lw  = (const float*)d_in[4];
  const float* c1_lb  = (const float*)d_in[5];
  const float* c1_rw  = (const float*)d_in[6];
  const float* c2_lw  = (const float*)d_in[7];
  const float* c2_lb  = (const float*)d_in[8];
  const float* c2_rw  = (const float*)d_in[9];
  float* ws  = (float*)d_ws;
  USH* xnb   = (USH*)(ws + OFF_XNB);
  USH* xnbT  = (USH*)(ws + OFF_XNBT);
  float* nrm = ws + OFF_NRM;
  float* w2  = ws + OFF_W2;
  float* t2v = ws + OFF_T2V;
  float* P1  = ws + OFF_P1;
  USH* M1T   = (USH*)(ws + OFF_M1T);
  USH* R1T   = (USH*)(ws + OFF_R1T);
  float* m2f = ws + OFF_M2F;
  float* r2f = ws + OFF_R2F;
  USH* w1b   = (USH*)(ws + OFF_P1);  // aliases P1 (P1 written only after gemm_h done)
  float* out = (float*)d_out;

  k_prep<<<dim3(99), dim3(256), 0, stream>>>(w1, c1_lw, c1_rw, c2_lw, c2_rw, w1b, R1T, r2f);
  k_gemm_h<<<dim3(BN / 32), dim3(512), 0, stream>>>(x, w1b, b1, xnb, xnbT, nrm);
  k_s1<<<dim3(NCH, BB), dim3(256), 0, stream>>>(xnbT, nrm, P1);
  k_m1_fused<<<dim3(16, BB), dim3(256), 0, stream>>>(P1, c1_lw, M1T);
  k_h1<<<dim3(BN / 64), dim3(256), 0, stream>>>(xnb, nrm, M1T, R1T, c1_lb, c2_lw, r2f, w2, t2v);
  k_m2<<<dim3(32, BB), dim3(256), 0, stream>>>(xnbT, w2, m2f);
  k_out<<<dim3(BN / 4), dim3(256), 0, stream>>>(xnb, m2f, t2v, c2_lb, mask, out);
}